// Round 9
// baseline (174.368 us; speedup 1.0000x reference)
//
#include <hip/hip_runtime.h>

#define NGRID 512
#define NV (NGRID * NGRID)          // 262144
#define NB 4
#define NVIEWS 4
#define FEPS 1e-6f
#define TR 2                        // owned rows per block
#define LDS_ROWS (TR + 2)           // + top/bottom halo
#define ROWF (NGRID * 3)            // 1536 floats per row
#define ROW4 (ROWF / 4)             // 384 float4 chunks per row
#define LDSF (LDS_ROWS * ROWF)      // 6144 floats = 24 KB

typedef float fvec4 __attribute__((ext_vector_type(4)));

static constexpr size_t NVF3 = (size_t)NV * 3;                      // 786432
static constexpr int    MAX4 = (int)(NVF3 / 4);                     // 196608
static constexpr size_t VERTS_FLOATS = (size_t)NVIEWS * NB * NVF3;  // 12,582,912
static constexpr size_t LAP_OFF = 2 * VERTS_FLOATS;
static constexpr size_t FLAT_OFF = LAP_OFF + 1;

__device__ __forceinline__ float frcp(float x)  { return __builtin_amdgcn_rcpf(x); }
__device__ __forceinline__ float fsqrt_(float x){ return __builtin_amdgcn_sqrtf(x); }

// ---------------------------------------------------------------------------
__global__ void init_losses(float* __restrict__ out) {
    if (threadIdx.x == 0) {
        out[LAP_OFF] = 0.0f;
        out[FLAT_OFF] = 0.0f;
    }
}

// ---------------------------------------------------------------------------
__device__ __forceinline__ float edge_val(float3 p0, float3 p1, float3 p2, float3 p3) {
    const float a1x = p1.x - p0.x, a1y = p1.y - p0.y, a1z = p1.z - p0.z;
    const float a1l2 = a1x * a1x + a1y * a1y + a1z * a1z;
    const float a1l1 = fsqrt_(a1l2 + FEPS);
    const float inv_a1l2 = frcp(a1l2 + FEPS);

    const float b1x = p2.x - p0.x, b1y = p2.y - p0.y, b1z = p2.z - p0.z;
    const float b1l2 = b1x * b1x + b1y * b1y + b1z * b1z;
    const float b1l1 = fsqrt_(b1l2 + FEPS);
    const float ab1 = a1x * b1x + a1y * b1y + a1z * b1z;
    const float cos1 = ab1 * frcp(a1l1 * b1l1 + FEPS);
    const float sin1 = fsqrt_(1.0f - cos1 * cos1 + FEPS);
    const float f1 = ab1 * inv_a1l2;
    const float cb1x = b1x - a1x * f1, cb1y = b1y - a1y * f1, cb1z = b1z - a1z * f1;
    const float l1 = b1l1 * sin1;

    const float b2x = p3.x - p0.x, b2y = p3.y - p0.y, b2z = p3.z - p0.z;
    const float b2l2 = b2x * b2x + b2y * b2y + b2z * b2z;
    const float b2l1 = fsqrt_(b2l2 + FEPS);
    const float ab2 = a1x * b2x + a1y * b2y + a1z * b2z;
    const float cos2 = ab2 * frcp(a1l1 * b2l1 + FEPS);
    const float sin2 = fsqrt_(1.0f - cos2 * cos2 + FEPS);
    const float f2 = ab2 * inv_a1l2;
    const float cb2x = b2x - a1x * f2, cb2y = b2y - a1y * f2, cb2z = b2z - a1z * f2;
    const float l2 = b2l1 * sin2;

    const float cosd = (cb1x * cb2x + cb1y * cb2y + cb1z * cb2z) * frcp(l1 * l2 + FEPS);
    const float t = cosd + 1.0f;
    return t * t;
}

// ---------------------------------------------------------------------------
// Mega-kernel v3: one block = (2-row tile, batch).
//  - All 9 global loads per thread (tv/disp x6 chunks + tex x3 owned chunks)
//    are issued in an explicit load-first block with clamped, unconditional
//    addresses -> max MLP (~144 B/thread in flight).
//  - Owned chunks use the store mapping (384 + qq*256 + tid): the transformed
//    vr is written to LDS AND stored to all 8 view streams straight from
//    registers. No separate store phase, no LDS re-read.
//  - Halo chunks (3/thread, wave-aligned mapping) go to LDS only.
//  - Loss phase: R8-verified 1x4 strip, 18 ds_read_b128 per thread.
__global__ __launch_bounds__(256) void mesh_fused_kernel(
    const float* __restrict__ disp, const float* __restrict__ center,
    const float* __restrict__ tex, const float* __restrict__ tv,
    float* __restrict__ out)
{
    // +4 chunks pad: strip reads at t=127 touch chunk 385 of the last row.
    __shared__ fvec4 vs4s[LDS_ROWS * ROW4 + 4];

    const int tid = threadIdx.x;
    const int b = blockIdx.y;
    const int R0 = blockIdx.x * TR;
    const int start4 = (R0 - 1) * ROW4;            // may be negative (tile 0)
    const int tile_base4 = R0 * ROW4;

    const float c0 = tanhf(center[b * 3 + 0]);
    const float c1 = tanhf(center[b * 3 + 1]);
    const float c2 = tanhf(center[b * 3 + 2]);
    const float carr[3] = {c0, c1, c2};

    const fvec4* __restrict__ tv4 = (const fvec4*)tv;
    const fvec4* __restrict__ d4p = (const fvec4*)(disp + (size_t)b * NVF3);
    const fvec4* __restrict__ t4p = (const fvec4*)(tex + (size_t)b * NVF3);
    fvec4* __restrict__ out4 = (fvec4*)out;

    // ---- Load-first block: all global reads issued before any compute ----
    // Owned chunks: ff4 = 384 + qq*256 + tid  (always in range).
    // Halo chunks:  idx = hh*256 + tid in [0,768); chunk = idx<384 ? idx : idx+768.
    fvec4 tvo[3], ddo[3], txo[3];      // owned
    fvec4 tvh[3], ddh[3];              // halo
    int hch[3];                        // halo chunk ids
    int hg4[3];                        // halo global chunk (unclamped)
#pragma unroll
    for (int qq = 0; qq < 3; ++qq) {
        const int g4 = tile_base4 + qq * 256 + tid;
        tvo[qq] = tv4[g4];
        ddo[qq] = d4p[g4];
        txo[qq] = t4p[g4];
    }
#pragma unroll
    for (int hh = 0; hh < 3; ++hh) {
        const int idx = hh * 256 + tid;
        const int chunk = (idx < ROW4) ? idx : idx + 768;
        const int g4 = start4 + chunk;
        int g4c = g4 < 0 ? 0 : (g4 >= MAX4 ? MAX4 - 1 : g4);
        hch[hh] = chunk;
        hg4[hh] = g4;
        tvh[hh] = tv4[g4c];
        ddh[hh] = d4p[g4c];
    }

    // ---- Transform + LDS write + fused 8-stream stores (owned) ----
#pragma unroll
    for (int qq = 0; qq < 3; ++qq) {
        const int ff4 = ROW4 + qq * 256 + tid;     // tile-local chunk
        fvec4 vr;
        int comp = ff4 % 3;                        // g4%3 == ff4%3 (start4%3==0)
#pragma unroll
        for (int l = 0; l < 4; ++l) {
            const float tvl = tvo[qq][l];
            const float s = fabsf(tvl);
            const float sgn = (tvl > 0.0f) ? 1.0f : -1.0f;
            const float e = __expf(-ddo[qq][l]);
            const float sigma = s * frcp(fmaf(1.0f - s, e, s));
            const float c = carr[comp];
            vr[l] = fmaf(sigma, sgn - c, c);
            comp = (comp == 2) ? 0 : comp + 1;
        }
        vs4s[ff4] = vr;
        const size_t pos4 = (size_t)tile_base4 + qq * 256 + tid;
#pragma unroll
        for (int view = 0; view < NVIEWS; ++view) {
            const size_t base = (size_t)(b * NVIEWS + view) * (NVF3 / 4);
            out4[base + pos4] = vr;
            out4[(VERTS_FLOATS / 4) + base + pos4] = txo[qq];
        }
    }

    // ---- Transform + LDS write (halo) ----
#pragma unroll
    for (int hh = 0; hh < 3; ++hh) {
        if (hg4[hh] < 0 || hg4[hh] >= MAX4) continue;   // tile-0 / last-tile edges
        const int ff4 = hch[hh];
        fvec4 vr;
        int comp = ff4 % 3;
#pragma unroll
        for (int l = 0; l < 4; ++l) {
            const float tvl = tvh[hh][l];
            const float s = fabsf(tvl);
            const float sgn = (tvl > 0.0f) ? 1.0f : -1.0f;
            const float e = __expf(-ddh[hh][l]);
            const float sigma = s * frcp(fmaf(1.0f - s, e, s));
            const float c = carr[comp];
            vr[l] = fmaf(sigma, sgn - c, c);
            comp = (comp == 2) ? 0 : comp + 1;
        }
        vs4s[ff4] = vr;
    }
    __syncthreads();

    // ---- Lap + flat losses: 1x4 strip per thread, 18 ds_read_b128 ----
    float lap_sum = 0.0f, flat_sum = 0.0f;
    {
        const int rofs = tid >> 7;             // owned tile row 0..1
        const int t = tid & 127;               // strip index
        const int cb = t * 4;                  // first owned column
        const int gr = R0 + rofs;              // global row (guards)
        const int lr = rofs + 1;               // LDS row of owned row

        // 3x6-chunk window: chunks j0+k, j0 = 3t-1 (clamped at t=0; the
        // clamped chunk only feeds col -1, which is guarded off).
        fvec4 wch[3][6];
        const int j0 = 3 * t - 1;
#pragma unroll
        for (int r = 0; r < 3; ++r) {
            const int rowbase4 = (lr - 1 + r) * ROW4;
#pragma unroll
            for (int k = 0; k < 6; ++k) {
                int jc = j0 + k;
                if (jc < 0) jc = 0;
                wch[r][k] = vs4s[rowbase4 + jc];
            }
        }

        // Component i of point p (col cb-1+p) in window row r:
        // float index 3p+1+i within the 24-float window.
#define GETC(r, p, i) (wch[r][(3 * (p) + 1 + (i)) >> 2][(3 * (p) + 1 + (i)) & 3])
#define GETP(r, p) make_float3(GETC(r, p, 0), GETC(r, p, 1), GETC(r, p, 2))

#pragma unroll
        for (int j = 0; j < 4; ++j) {
            const int c = cb + j;
            const float3 C  = GETP(1, j + 1);
            const float3 Nn = GETP(0, j + 1);
            const float3 S  = GETP(2, j + 1);
            const float3 W  = GETP(1, j);
            const float3 E  = GETP(1, j + 2);
            const float3 NE = GETP(0, j + 2);
            const float3 SW = GETP(2, j);
            const float3 SE = GETP(2, j + 2);

            // Laplacian (6-neighborhood of the unique-edge graph)
            {
                float sx = 0.f, sy = 0.f, sz = 0.f;
                int deg = 0;
                if (gr > 0)               { sx += Nn.x; sy += Nn.y; sz += Nn.z; deg++; }
                if (gr < NGRID - 1)       { sx += S.x;  sy += S.y;  sz += S.z;  deg++; }
                if (c > 0)                { sx += W.x;  sy += W.y;  sz += W.z;  deg++; }
                if (c < NGRID - 1)        { sx += E.x;  sy += E.y;  sz += E.z;  deg++; }
                if (gr > 0 && c < NGRID - 1)      { sx += NE.x; sy += NE.y; sz += NE.z; deg++; }
                if (gr < NGRID - 1 && c > 0)      { sx += SW.x; sy += SW.y; sz += SW.z; deg++; }
                const float id = frcp((float)deg);
                const float lx = C.x - sx * id;
                const float ly = C.y - sy * id;
                const float lz = C.z - sz * id;
                lap_sum += lx * lx + ly * ly + lz * lz;
            }

            // Flat loss: up to 3 structural edges anchored at (gr, c)
            if (gr < NGRID - 1 && c < NGRID - 1) {
                flat_sum += edge_val(E, S, C, SE);
            }
            if (gr >= 1 && gr < NGRID - 1 && c < NGRID - 1) {
                flat_sum += edge_val(C, E, S, NE);
            }
            if (gr < NGRID - 1 && c >= 1 && c < NGRID - 1) {
                flat_sum += edge_val(C, S, E, SW);
            }
        }
#undef GETC
#undef GETP
    }

    // ---- Block reduction (two values), one atomic pair per block ----
#pragma unroll
    for (int off = 32; off > 0; off >>= 1) {
        lap_sum  += __shfl_down(lap_sum, off, 64);
        flat_sum += __shfl_down(flat_sum, off, 64);
    }
    __shared__ float red[8];
    const int lane = tid & 63;
    const int wid = tid >> 6;
    if (lane == 0) { red[wid] = lap_sum; red[4 + wid] = flat_sum; }
    __syncthreads();
    if (tid == 0) {
        const float ls = red[0] + red[1] + red[2] + red[3];
        const float fs = red[4] + red[5] + red[6] + red[7];
        atomicAdd(&out[LAP_OFF],  ls * (1.0f / NB));
        atomicAdd(&out[FLAT_OFF], fs * (1.0f / NB));
    }
}

// ---------------------------------------------------------------------------
extern "C" void kernel_launch(void* const* d_in, const int* in_sizes, int n_in,
                              void* d_out, int out_size, void* d_ws, size_t ws_size,
                              hipStream_t stream)
{
    const float* disp   = (const float*)d_in[0];
    const float* center = (const float*)d_in[1];
    const float* tex    = (const float*)d_in[2];
    const float* tv     = (const float*)d_in[3];
    float* out = (float*)d_out;

    init_losses<<<1, 64, 0, stream>>>(out);
    mesh_fused_kernel<<<dim3(NGRID / TR, NB), 256, 0, stream>>>(disp, center, tex, tv, out);
}